// Round 7
// baseline (543.887 us; speedup 1.0000x reference)
//
#include <hip/hip_runtime.h>
#include <hip/hip_fp16.h>

#define N_GRAPHS_C 256
#define CHUNK_LOG 13
#define CHUNK (1 << CHUNK_LOG)   // 8192 atoms per bucket
#define MAXB 32
#define NSLICE 20                // passB slices per bucket (64 KB LDS -> 2 blocks/CU)
#define NSLICE_FB 10
#define TILE_G 1024              // int4 groups per passA block = 4096 edges (8 blocks/CU)
#define TPA 256
#define TPBB 1024

// ---------------- shared per-edge math ----------------
// Units: Angstrom, electron charge, eV (avoids fp32 denormals from the
// reference's SI-unit charges; algebraically identical).
__device__ __forceinline__ void edge_math(
    float dx, float dy, float dz, float qr, float qc, float gA,
    float& fx, float& fy, float& fz, float& ecoul)
{
    const float KEV = (float)(8987551792.3 * 1.602176634e-9); // 14.3996 eV*A/e^2
    float r2 = dx * dx + dy * dy + dz * dz;
    float inv_r = rsqrtf(r2);
    float rA = r2 * inv_r;

    float pref = KEV * qr * qc * inv_r;

    float damp = 1.0f;
    if (rA < 2.2f)
        damp = __expf(-18.7f * (2.2f - rA) * (1.0f / 2.2f));

    float grij = gA * rA;
    float expm2 = __expf(-grij * grij);
    float t = 1.0f / (1.0f + 0.3275911f * grij);
    float erfc = t * (0.254829592f +
                 t * (-0.284496736f +
                 t * (1.421413741f +
                 t * (-1.453152027f +
                 t * 1.061405429f)))) * expm2;

    ecoul = pref * (0.5f * damp + (erfc - 1.0f));
    float S = damp + erfc + 2.0f * grij * expm2 - 1.0f;
    float fs = pref * S * (inv_r * inv_r);
    fx = dx * fs; fy = dy * fs; fz = dz * fs;
}

__device__ __forceinline__ uint2 pack_rec(float fx, float fy, float fz, unsigned lid)
{
    uint2 u;
    u.x = __builtin_bit_cast(unsigned, __floats2half2_rn(fx, fy));
    u.y = (__builtin_bit_cast(unsigned, __floats2half2_rn(fz, 0.0f)) & 0xFFFFu) |
          (lid << 16);
    return u;
}

// ================= fast path =================
// passA: dense single sweep. 1954 blocks (8/CU -> full occupancy for latency
// hiding of the global loads + ds_add_rtn->store chain). 8 B records halve
// the write stream vs round 6.
__global__ __launch_bounds__(TPA) void passA(
    const float* __restrict__ dij, const float* __restrict__ q,
    const float* __restrict__ g_ewald,
    const int* __restrict__ row, const int* __restrict__ col,
    const int* __restrict__ batch,
    uint2* __restrict__ records, int cap,
    unsigned* __restrict__ cnt_table,
    float* __restrict__ e_part,
    float* __restrict__ ovf,
    int n_edges, int nb)
{
    __shared__ unsigned cnt[MAXB];
    __shared__ float e_graph[4 * N_GRAPHS_C];   // per-wave replicas

    int tid = threadIdx.x;
    if (tid < MAXB) cnt[tid] = 0u;
    for (int i = tid; i < 4 * N_GRAPHS_C; i += TPA) e_graph[i] = 0.f;
    __syncthreads();

    float* e_my = &e_graph[(tid >> 6) * N_GRAPHS_C];

    int n4 = n_edges >> 2;
    int g0 = blockIdx.x * TILE_G;
    int g1 = min(g0 + TILE_G, n4);

    const int4* row4 = (const int4*)row;
    const int4* col4 = (const int4*)col;
    const float4* dij4 = (const float4*)dij;

    const float gA = g_ewald[0] * 1e-10f;    // 1/m -> 1/Angstrom
    size_t blk_base = (size_t)blockIdx.x * nb * cap;

    for (int g = g0 + tid; g < g1; g += TPA) {
        int4 r4 = row4[g];
        int4 c4 = col4[g];
        float4 d0 = dij4[3 * g + 0];
        float4 d1 = dij4[3 * g + 1];
        float4 d2 = dij4[3 * g + 2];
        float ex[4] = {d0.x, d0.w, d1.z, d2.y};
        float ey[4] = {d0.y, d1.x, d1.w, d2.z};
        float ez[4] = {d0.z, d1.y, d2.x, d2.w};
        int rr[4] = {r4.x, r4.y, r4.z, r4.w};
        int cc[4] = {c4.x, c4.y, c4.z, c4.w};
        #pragma unroll
        for (int j = 0; j < 4; ++j) {
            int r = rr[j], c = cc[j];
            float fx, fy, fz, ec;
            edge_math(ex[j], ey[j], ez[j], q[r], q[c], gA, fx, fy, fz, ec);

            atomicAdd(&e_my[batch[r]], ec);

            int br = r >> CHUNK_LOG, bc = c >> CHUNK_LOG;
            unsigned pr = atomicAdd(&cnt[br], 1u);
            unsigned pc = atomicAdd(&cnt[bc], 1u);
            if (pr < (unsigned)cap)
                records[blk_base + (size_t)br * cap + pr] =
                    pack_rec(fx, fy, fz, (unsigned)(r & (CHUNK - 1)));
            else {
                atomicAdd(&ovf[3 * r + 0], fx);
                atomicAdd(&ovf[3 * r + 1], fy);
                atomicAdd(&ovf[3 * r + 2], fz);
            }
            if (pc < (unsigned)cap)
                records[blk_base + (size_t)bc * cap + pc] =
                    pack_rec(-fx, -fy, -fz, (unsigned)(c & (CHUNK - 1)));
            else {
                atomicAdd(&ovf[3 * c + 0], -fx);
                atomicAdd(&ovf[3 * c + 1], -fy);
                atomicAdd(&ovf[3 * c + 2], -fz);
            }
        }
    }
    __syncthreads();

    if (tid < nb) cnt_table[(size_t)blockIdx.x * nb + tid] = min(cnt[tid], (unsigned)cap);
    for (int g2 = tid; g2 < N_GRAPHS_C; g2 += TPA)
        e_part[(size_t)blockIdx.x * N_GRAPHS_C + g2] =
            e_graph[g2] + e_graph[N_GRAPHS_C + g2] +
            e_graph[2 * N_GRAPHS_C + g2] + e_graph[3 * N_GRAPHS_C + g2];
}

// passB: block (b,s); each WAVE takes whole runs (runs are only ~330 records
// now, so block-wide striding would idle most waves). Records are 8 B:
// v.x = half2(fx,fy), v.y = half(fz) | idx<<16. 2 ds_pk_add_f16 per record
// into the 64 KB half2-packed accumulator.
__global__ __launch_bounds__(TPBB) void passB(
    const uint2* __restrict__ records, int cap,
    const unsigned* __restrict__ cnt_table,
    unsigned* __restrict__ partial, int nblkA, int nb, int nslice)
{
    __shared__ unsigned acc[2 * CHUNK];   // [0..CHUNK): (fx,fy); [CHUNK..): (fz,0)

    int b = blockIdx.x / nslice;
    int s = blockIdx.x % nslice;
    int k0 = (int)((long long)s * nblkA / nslice);
    int k1 = (int)((long long)(s + 1) * nblkA / nslice);

    for (int i = threadIdx.x; i < 2 * CHUNK; i += TPBB) acc[i] = 0u;
    __syncthreads();

    unsigned lds_base = (unsigned)(size_t)&acc[0];
    int wid  = threadIdx.x >> 6;
    int lane = threadIdx.x & 63;

    for (int k = k0 + wid; k < k1; k += TPBB / 64) {
        unsigned n = cnt_table[(size_t)k * nb + b];       // wave-uniform
        const uint2* rec = records + ((size_t)k * nb + b) * cap;
        for (unsigned i = lane; i < n; i += 64) {
            uint2 v = rec[i];
            unsigned idx = v.y >> 16;
            asm volatile("ds_pk_add_f16 %0, %1"
                         :: "v"(lds_base + 4u * idx), "v"(v.x) : "memory");
            asm volatile("ds_pk_add_f16 %0, %1"
                         :: "v"(lds_base + 4u * (CHUNK + idx)), "v"(v.y & 0xFFFFu)
                         : "memory");
        }
    }
    asm volatile("s_waitcnt lgkmcnt(0)" ::: "memory");
    __syncthreads();

    unsigned* dst = partial + (size_t)blockIdx.x * 2 * CHUNK;
    for (int i = threadIdx.x; i < 2 * CHUNK; i += TPBB) dst[i] = acc[i];
}

__global__ __launch_bounds__(256) void fin_force(
    const unsigned* __restrict__ partial, const float* __restrict__ ovf,
    float* __restrict__ force, int n_atoms, int nslice)
{
    int a = blockIdx.x * 256 + threadIdx.x;
    if (a >= n_atoms) return;
    int b = a >> CHUNK_LOG, l = a & (CHUNK - 1);
    float fx = ovf[3 * a + 0], fy = ovf[3 * a + 1], fz = ovf[3 * a + 2];
    const unsigned* p = partial + (size_t)b * nslice * 2 * CHUNK + l;
    for (int s = 0; s < nslice; ++s) {
        const unsigned* ps = p + (size_t)s * 2 * CHUNK;
        float2 f1 = __half22float2(__builtin_bit_cast(__half2, ps[0]));
        float2 f2 = __half22float2(__builtin_bit_cast(__half2, ps[CHUNK]));
        fx += f1.x; fy += f1.y; fz += f2.x;
    }
    force[3 * a + 0] = fx;
    force[3 * a + 1] = fy;
    force[3 * a + 2] = fz;
}

__global__ __launch_bounds__(64) void fin_energy(
    const float* __restrict__ e_part, float* __restrict__ energy, int nblkA)
{
    int g = blockIdx.x;
    float s = 0.f;
    for (int k = threadIdx.x; k < nblkA; k += 64)
        s += e_part[(size_t)k * N_GRAPHS_C + g];
    for (int off = 32; off > 0; off >>= 1) s += __shfl_down(s, off, 64);
    if (threadIdx.x == 0) energy[g] = s;
}

// ================= fallback: round-3 chunk-scan path =================
__global__ __launch_bounds__(1024) void chunk_kernel(
    const float* __restrict__ dij, const float* __restrict__ q,
    const float* __restrict__ g_ewald,
    const int* __restrict__ row, const int* __restrict__ col,
    float* __restrict__ partial, int n_edges, int n_chunks, int n_slices)
{
    __shared__ float acc[CHUNK * 4];
    int c = blockIdx.x % n_chunks;
    int p = blockIdx.x / n_chunks;
    int cbase = c << CHUNK_LOG;
    for (int i = threadIdx.x; i < CHUNK * 4; i += 1024) acc[i] = 0.f;
    __syncthreads();
    const float gA = g_ewald[0] * 1e-10f;
    int n4 = (n_edges + 3) >> 2;
    int g0 = (int)((long long)p * n4 / n_slices);
    int g1 = (int)((long long)(p + 1) * n4 / n_slices);
    const int4* row4 = (const int4*)row;
    const int4* col4 = (const int4*)col;
    for (int g = g0 + threadIdx.x; g < g1; g += 1024) {
        int4 r4 = row4[g];
        int4 c4 = col4[g];
        int rr[4] = {r4.x, r4.y, r4.z, r4.w};
        int cc[4] = {c4.x, c4.y, c4.z, c4.w};
        #pragma unroll
        for (int j = 0; j < 4; ++j) {
            int e = 4 * g + j;
            if (e >= n_edges) break;
            int rl = rr[j] - cbase;
            int cl = cc[j] - cbase;
            bool hr = (unsigned)rl < (unsigned)CHUNK;
            bool hc = (unsigned)cl < (unsigned)CHUNK;
            if (!(hr || hc)) continue;
            float fx, fy, fz, ec;
            edge_math(dij[3 * e], dij[3 * e + 1], dij[3 * e + 2],
                      q[rr[j]], q[cc[j]], gA, fx, fy, fz, ec);
            if (hr) {
                atomicAdd(&acc[4 * rl + 0], fx);
                atomicAdd(&acc[4 * rl + 1], fy);
                atomicAdd(&acc[4 * rl + 2], fz);
                atomicAdd(&acc[4 * rl + 3], ec);
            }
            if (hc) {
                atomicAdd(&acc[4 * cl + 0], -fx);
                atomicAdd(&acc[4 * cl + 1], -fy);
                atomicAdd(&acc[4 * cl + 2], -fz);
            }
        }
    }
    __syncthreads();
    float4* dst = (float4*)partial + (size_t)(c * n_slices + p) * CHUNK;
    const float4* src = (const float4*)acc;
    for (int i = threadIdx.x; i < CHUNK; i += 1024) dst[i] = src[i];
}

__global__ __launch_bounds__(256) void finalize_kernel(
    const float* __restrict__ partial, const int* __restrict__ batch,
    float* __restrict__ energy, float* __restrict__ force,
    int n_atoms, int n_slices)
{
    int i = blockIdx.x * blockDim.x + threadIdx.x;
    float fx = 0.f, fy = 0.f, fz = 0.f, en = 0.f;
    if (i < n_atoms) {
        int c = i >> CHUNK_LOG;
        int l = i & (CHUNK - 1);
        const float4* base = (const float4*)partial + (size_t)c * n_slices * CHUNK + l;
        for (int p = 0; p < n_slices; ++p) {
            float4 v = base[(size_t)p * CHUNK];
            fx += v.x; fy += v.y; fz += v.z; en += v.w;
        }
        force[3 * i + 0] = fx;
        force[3 * i + 1] = fy;
        force[3 * i + 2] = fz;
    }
    int ic = i < n_atoms ? i : (n_atoms - 1);
    int b = batch[ic];
    float v = (i < n_atoms) ? en : 0.0f;
    int b0 = __shfl(b, 0, 64);
    unsigned long long m = __ballot(b == b0);
    if (m == ~0ull) {
        for (int off = 32; off > 0; off >>= 1)
            v += __shfl_down(v, off, 64);
        if ((threadIdx.x & 63) == 0) atomicAdd(&energy[b0], v);
    } else {
        atomicAdd(&energy[b], v);
    }
}

extern "C" void kernel_launch(void* const* d_in, const int* in_sizes, int n_in,
                              void* d_out, int out_size, void* d_ws, size_t ws_size,
                              hipStream_t stream) {
    const float* dij     = (const float*)d_in[0];
    const float* q       = (const float*)d_in[1];
    const float* g_ewald = (const float*)d_in[2];
    const int*   row     = (const int*)d_in[3];
    const int*   col     = (const int*)d_in[4];
    const int*   batch   = (const int*)d_in[5];

    int n_edges = in_sizes[0] / 3;
    int n_atoms = in_sizes[1];

    float* energy = (float*)d_out;               // [256]
    float* force  = (float*)d_out + N_GRAPHS_C;  // [n_atoms*3]

    int nb = (n_atoms + CHUNK - 1) >> CHUNK_LOG;            // 25
    int n4 = n_edges >> 2;
    int nblkA = (n4 + TILE_G - 1) / TILE_G;                 // 1954

    size_t sz_partial = (size_t)nb * NSLICE * 2 * CHUNK * sizeof(unsigned); // 32.8 MB
    size_t sz_epart   = (size_t)nblkA * N_GRAPHS_C * sizeof(float);         // 2 MB
    size_t sz_cnt     = (size_t)nblkA * nb * sizeof(unsigned);
    size_t sz_ovf     = (size_t)3 * n_atoms * sizeof(float);
    size_t fixed = ((sz_partial + 255) & ~(size_t)255) +
                   ((sz_epart   + 255) & ~(size_t)255) +
                   ((sz_cnt     + 255) & ~(size_t)255) +
                   ((sz_ovf     + 255) & ~(size_t)255) + 512;

    int cap = 0;
    if ((long long)ws_size > (long long)fixed) {
        long long c = ((long long)ws_size - (long long)fixed) /
                      ((long long)nblkA * nb * 8);
        c = (c / 32) * 32;
        if (c > 640) c = 640;     // mean/bucket ~328, sigma ~18 -> 640 is huge margin
        cap = (int)c;
    }

    bool fast = (nb <= MAXB) && ((n_edges & 3) == 0) && (cap >= 416);

    if (fast) {
        char* ws = (char*)d_ws;
        size_t off = 0;
        uint2*    records  = (uint2*)(ws + off);
        off += (size_t)nblkA * nb * cap * 8;   off = (off + 255) & ~(size_t)255;
        unsigned* partial  = (unsigned*)(ws + off);
        off += sz_partial;                     off = (off + 255) & ~(size_t)255;
        float*    e_part   = (float*)(ws + off);
        off += sz_epart;                       off = (off + 255) & ~(size_t)255;
        unsigned* cnt_tab  = (unsigned*)(ws + off);
        off += sz_cnt;                         off = (off + 255) & ~(size_t)255;
        float*    ovf      = (float*)(ws + off);

        hipMemsetAsync(ovf, 0, sz_ovf, stream);

        passA<<<nblkA, TPA, 0, stream>>>(
            dij, q, g_ewald, row, col, batch,
            records, cap, cnt_tab, e_part, ovf, n_edges, nb);

        passB<<<nb * NSLICE, TPBB, 0, stream>>>(
            records, cap, cnt_tab, partial, nblkA, nb, NSLICE);

        fin_force<<<(n_atoms + 255) / 256, 256, 0, stream>>>(
            partial, ovf, force, n_atoms, NSLICE);

        fin_energy<<<N_GRAPHS_C, 64, 0, stream>>>(e_part, energy, nblkA);
    } else {
        size_t need_chunk = (size_t)nb * NSLICE_FB * CHUNK * 4 * sizeof(float);
        if (ws_size >= need_chunk) {
            hipMemsetAsync(d_out, 0, N_GRAPHS_C * sizeof(float), stream);
            chunk_kernel<<<nb * NSLICE_FB, 1024, 0, stream>>>(
                dij, q, g_ewald, row, col, (float*)d_ws, n_edges, nb, NSLICE_FB);
            finalize_kernel<<<(n_atoms + 255) / 256, 256, 0, stream>>>(
                (const float*)d_ws, batch, energy, force, n_atoms, NSLICE_FB);
        }
    }
}

// Round 8
// 501.935 us; speedup vs baseline: 1.0836x; 1.0836x over previous
//
#include <hip/hip_runtime.h>
#include <hip/hip_fp16.h>

#define N_GRAPHS_C 256
#define CHUNK_LOG 13
#define CHUNK (1 << CHUNK_LOG)   // 8192 atoms per bucket
#define MAXB 32
#define NSLICE 20                // passB slices per bucket (64 KB LDS -> 2 blocks/CU)
#define NSLICE_FB 10
#define TILE_G 2048              // int4 groups per passA block = 8192 edges
#define TPA 256
#define TPBB 1024

// ---------------- shared per-edge math ----------------
// Units: Angstrom, electron charge, eV (avoids fp32 denormals from the
// reference's SI-unit charges; algebraically identical).
__device__ __forceinline__ void edge_math(
    float dx, float dy, float dz, float qr, float qc, float gA,
    float& fx, float& fy, float& fz, float& ecoul)
{
    const float KEV = (float)(8987551792.3 * 1.602176634e-9); // 14.3996 eV*A/e^2
    float r2 = dx * dx + dy * dy + dz * dz;
    float inv_r = rsqrtf(r2);
    float rA = r2 * inv_r;

    float pref = KEV * qr * qc * inv_r;

    float damp = 1.0f;
    if (rA < 2.2f)
        damp = __expf(-18.7f * (2.2f - rA) * (1.0f / 2.2f));

    float grij = gA * rA;
    float expm2 = __expf(-grij * grij);
    float t = 1.0f / (1.0f + 0.3275911f * grij);
    float erfc = t * (0.254829592f +
                 t * (-0.284496736f +
                 t * (1.421413741f +
                 t * (-1.453152027f +
                 t * 1.061405429f)))) * expm2;

    ecoul = pref * (0.5f * damp + (erfc - 1.0f));
    float S = damp + erfc + 2.0f * grij * expm2 - 1.0f;
    float fs = pref * S * (inv_r * inv_r);
    fx = dx * fs; fy = dy * fs; fz = dz * fs;
}

__device__ __forceinline__ uint2 pack_rec(float fx, float fy, float fz, unsigned lid)
{
    uint2 u;
    u.x = __builtin_bit_cast(unsigned, __floats2half2_rn(fx, fy));
    u.y = (__builtin_bit_cast(unsigned, __floats2half2_rn(fz, 0.0f)) & 0xFFFFu) |
          (lid << 16);
    return u;
}

// prep: fuse q[] and batch[] into one 8 B table so passA does 2 scattered
// gathers per edge instead of 3 (passA is scattered-transaction bound).
__global__ __launch_bounds__(256) void prep_qg(
    const float* __restrict__ q, const int* __restrict__ batch,
    float2* __restrict__ qg, int n_atoms)
{
    int i = blockIdx.x * 256 + threadIdx.x;
    if (i < n_atoms)
        qg[i] = make_float2(q[i], __int_as_float(batch[i]));
}

// ================= fast path =================
// passA: dense single sweep. Per edge: 2 scattered 8 B gathers (qg[r], qg[c]),
// ~50 VALU of math, 1 LDS energy atomic, 2 LDS rank atomics, 2 scattered 8 B
// record stores. Fixed per-(block,bucket) capacity; overflow -> ovf[].
__global__ __launch_bounds__(TPA) void passA(
    const float* __restrict__ dij, const float2* __restrict__ qg,
    const float* __restrict__ g_ewald,
    const int* __restrict__ row, const int* __restrict__ col,
    uint2* __restrict__ records, int cap,
    unsigned* __restrict__ cnt_table,
    float* __restrict__ e_part,
    float* __restrict__ ovf,
    int n_edges, int nb)
{
    __shared__ unsigned cnt[MAXB];
    __shared__ float e_graph[4 * N_GRAPHS_C];   // per-wave replicas

    int tid = threadIdx.x;
    if (tid < MAXB) cnt[tid] = 0u;
    for (int i = tid; i < 4 * N_GRAPHS_C; i += TPA) e_graph[i] = 0.f;
    __syncthreads();

    float* e_my = &e_graph[(tid >> 6) * N_GRAPHS_C];

    int n4 = n_edges >> 2;
    int g0 = blockIdx.x * TILE_G;
    int g1 = min(g0 + TILE_G, n4);

    const int4* row4 = (const int4*)row;
    const int4* col4 = (const int4*)col;
    const float4* dij4 = (const float4*)dij;

    const float gA = g_ewald[0] * 1e-10f;    // 1/m -> 1/Angstrom
    size_t blk_base = (size_t)blockIdx.x * nb * cap;

    for (int g = g0 + tid; g < g1; g += TPA) {
        int4 r4 = row4[g];
        int4 c4 = col4[g];
        float4 d0 = dij4[3 * g + 0];
        float4 d1 = dij4[3 * g + 1];
        float4 d2 = dij4[3 * g + 2];
        float ex[4] = {d0.x, d0.w, d1.z, d2.y};
        float ey[4] = {d0.y, d1.x, d1.w, d2.z};
        float ez[4] = {d0.z, d1.y, d2.x, d2.w};
        int rr[4] = {r4.x, r4.y, r4.z, r4.w};
        int cc[4] = {c4.x, c4.y, c4.z, c4.w};
        #pragma unroll
        for (int j = 0; j < 4; ++j) {
            int r = rr[j], c = cc[j];
            float2 vr = qg[r];
            float2 vc = qg[c];
            float fx, fy, fz, ec;
            edge_math(ex[j], ey[j], ez[j], vr.x, vc.x, gA, fx, fy, fz, ec);

            atomicAdd(&e_my[__float_as_int(vr.y)], ec);

            int br = r >> CHUNK_LOG, bc = c >> CHUNK_LOG;
            unsigned pr = atomicAdd(&cnt[br], 1u);
            unsigned pc = atomicAdd(&cnt[bc], 1u);
            if (pr < (unsigned)cap)
                records[blk_base + (size_t)br * cap + pr] =
                    pack_rec(fx, fy, fz, (unsigned)(r & (CHUNK - 1)));
            else {
                atomicAdd(&ovf[3 * r + 0], fx);
                atomicAdd(&ovf[3 * r + 1], fy);
                atomicAdd(&ovf[3 * r + 2], fz);
            }
            if (pc < (unsigned)cap)
                records[blk_base + (size_t)bc * cap + pc] =
                    pack_rec(-fx, -fy, -fz, (unsigned)(c & (CHUNK - 1)));
            else {
                atomicAdd(&ovf[3 * c + 0], -fx);
                atomicAdd(&ovf[3 * c + 1], -fy);
                atomicAdd(&ovf[3 * c + 2], -fz);
            }
        }
    }
    __syncthreads();

    if (tid < nb) cnt_table[(size_t)blockIdx.x * nb + tid] = min(cnt[tid], (unsigned)cap);
    for (int g2 = tid; g2 < N_GRAPHS_C; g2 += TPA)
        e_part[(size_t)blockIdx.x * N_GRAPHS_C + g2] =
            e_graph[g2] + e_graph[N_GRAPHS_C + g2] +
            e_graph[2 * N_GRAPHS_C + g2] + e_graph[3 * N_GRAPHS_C + g2];
}

// passB: block (b,s); each WAVE takes whole runs (~655 records, ~10 full
// wave-iterations). No "memory" clobber on the DS asm: volatile preserves
// DS-op ordering but lets the compiler hoist record loads ahead of the DS
// chain. 2 ds_pk_add_f16 per record into the 64 KB half2 accumulator.
__global__ __launch_bounds__(TPBB) void passB(
    const uint2* __restrict__ records, int cap,
    const unsigned* __restrict__ cnt_table,
    unsigned* __restrict__ partial, int nblkA, int nb, int nslice)
{
    __shared__ unsigned acc[2 * CHUNK];   // [0..CHUNK): (fx,fy); [CHUNK..): (fz,0)

    int b = blockIdx.x / nslice;
    int s = blockIdx.x % nslice;
    int k0 = (int)((long long)s * nblkA / nslice);
    int k1 = (int)((long long)(s + 1) * nblkA / nslice);

    for (int i = threadIdx.x; i < 2 * CHUNK; i += TPBB) acc[i] = 0u;
    __syncthreads();

    unsigned lds_base = (unsigned)(size_t)&acc[0];
    int wid  = threadIdx.x >> 6;
    int lane = threadIdx.x & 63;

    for (int k = k0 + wid; k < k1; k += TPBB / 64) {
        unsigned n = cnt_table[(size_t)k * nb + b];       // wave-uniform
        const uint2* rec = records + ((size_t)k * nb + b) * cap;
        for (unsigned i = lane; i < n; i += 64) {
            uint2 v = rec[i];
            unsigned idx = v.y >> 16;
            asm volatile("ds_pk_add_f16 %0, %1"
                         :: "v"(lds_base + 4u * idx), "v"(v.x));
            asm volatile("ds_pk_add_f16 %0, %1"
                         :: "v"(lds_base + 4u * (CHUNK + idx)), "v"(v.y & 0xFFFFu));
        }
    }
    asm volatile("s_waitcnt lgkmcnt(0)" ::: "memory");
    __syncthreads();

    unsigned* dst = partial + (size_t)blockIdx.x * 2 * CHUNK;
    for (int i = threadIdx.x; i < 2 * CHUNK; i += TPBB) dst[i] = acc[i];
}

__global__ __launch_bounds__(256) void fin_force(
    const unsigned* __restrict__ partial, const float* __restrict__ ovf,
    float* __restrict__ force, int n_atoms, int nslice)
{
    int a = blockIdx.x * 256 + threadIdx.x;
    if (a >= n_atoms) return;
    int b = a >> CHUNK_LOG, l = a & (CHUNK - 1);
    float fx = ovf[3 * a + 0], fy = ovf[3 * a + 1], fz = ovf[3 * a + 2];
    const unsigned* p = partial + (size_t)b * nslice * 2 * CHUNK + l;
    for (int s = 0; s < nslice; ++s) {
        const unsigned* ps = p + (size_t)s * 2 * CHUNK;
        float2 f1 = __half22float2(__builtin_bit_cast(__half2, ps[0]));
        float2 f2 = __half22float2(__builtin_bit_cast(__half2, ps[CHUNK]));
        fx += f1.x; fy += f1.y; fz += f2.x;
    }
    force[3 * a + 0] = fx;
    force[3 * a + 1] = fy;
    force[3 * a + 2] = fz;
}

__global__ __launch_bounds__(64) void fin_energy(
    const float* __restrict__ e_part, float* __restrict__ energy, int nblkA)
{
    int g = blockIdx.x;
    float s = 0.f;
    for (int k = threadIdx.x; k < nblkA; k += 64)
        s += e_part[(size_t)k * N_GRAPHS_C + g];
    for (int off = 32; off > 0; off >>= 1) s += __shfl_down(s, off, 64);
    if (threadIdx.x == 0) energy[g] = s;
}

// ================= fallback: round-3 chunk-scan path =================
__global__ __launch_bounds__(1024) void chunk_kernel(
    const float* __restrict__ dij, const float* __restrict__ q,
    const float* __restrict__ g_ewald,
    const int* __restrict__ row, const int* __restrict__ col,
    float* __restrict__ partial, int n_edges, int n_chunks, int n_slices)
{
    __shared__ float acc[CHUNK * 4];
    int c = blockIdx.x % n_chunks;
    int p = blockIdx.x / n_chunks;
    int cbase = c << CHUNK_LOG;
    for (int i = threadIdx.x; i < CHUNK * 4; i += 1024) acc[i] = 0.f;
    __syncthreads();
    const float gA = g_ewald[0] * 1e-10f;
    int n4 = (n_edges + 3) >> 2;
    int g0 = (int)((long long)p * n4 / n_slices);
    int g1 = (int)((long long)(p + 1) * n4 / n_slices);
    const int4* row4 = (const int4*)row;
    const int4* col4 = (const int4*)col;
    for (int g = g0 + threadIdx.x; g < g1; g += 1024) {
        int4 r4 = row4[g];
        int4 c4 = col4[g];
        int rr[4] = {r4.x, r4.y, r4.z, r4.w};
        int cc[4] = {c4.x, c4.y, c4.z, c4.w};
        #pragma unroll
        for (int j = 0; j < 4; ++j) {
            int e = 4 * g + j;
            if (e >= n_edges) break;
            int rl = rr[j] - cbase;
            int cl = cc[j] - cbase;
            bool hr = (unsigned)rl < (unsigned)CHUNK;
            bool hc = (unsigned)cl < (unsigned)CHUNK;
            if (!(hr || hc)) continue;
            float fx, fy, fz, ec;
            edge_math(dij[3 * e], dij[3 * e + 1], dij[3 * e + 2],
                      q[rr[j]], q[cc[j]], gA, fx, fy, fz, ec);
            if (hr) {
                atomicAdd(&acc[4 * rl + 0], fx);
                atomicAdd(&acc[4 * rl + 1], fy);
                atomicAdd(&acc[4 * rl + 2], fz);
                atomicAdd(&acc[4 * rl + 3], ec);
            }
            if (hc) {
                atomicAdd(&acc[4 * cl + 0], -fx);
                atomicAdd(&acc[4 * cl + 1], -fy);
                atomicAdd(&acc[4 * cl + 2], -fz);
            }
        }
    }
    __syncthreads();
    float4* dst = (float4*)partial + (size_t)(c * n_slices + p) * CHUNK;
    const float4* src = (const float4*)acc;
    for (int i = threadIdx.x; i < CHUNK; i += 1024) dst[i] = src[i];
}

__global__ __launch_bounds__(256) void finalize_kernel(
    const float* __restrict__ partial, const int* __restrict__ batch,
    float* __restrict__ energy, float* __restrict__ force,
    int n_atoms, int n_slices)
{
    int i = blockIdx.x * blockDim.x + threadIdx.x;
    float fx = 0.f, fy = 0.f, fz = 0.f, en = 0.f;
    if (i < n_atoms) {
        int c = i >> CHUNK_LOG;
        int l = i & (CHUNK - 1);
        const float4* base = (const float4*)partial + (size_t)c * n_slices * CHUNK + l;
        for (int p = 0; p < n_slices; ++p) {
            float4 v = base[(size_t)p * CHUNK];
            fx += v.x; fy += v.y; fz += v.z; en += v.w;
        }
        force[3 * i + 0] = fx;
        force[3 * i + 1] = fy;
        force[3 * i + 2] = fz;
    }
    int ic = i < n_atoms ? i : (n_atoms - 1);
    int b = batch[ic];
    float v = (i < n_atoms) ? en : 0.0f;
    int b0 = __shfl(b, 0, 64);
    unsigned long long m = __ballot(b == b0);
    if (m == ~0ull) {
        for (int off = 32; off > 0; off >>= 1)
            v += __shfl_down(v, off, 64);
        if ((threadIdx.x & 63) == 0) atomicAdd(&energy[b0], v);
    } else {
        atomicAdd(&energy[b], v);
    }
}

extern "C" void kernel_launch(void* const* d_in, const int* in_sizes, int n_in,
                              void* d_out, int out_size, void* d_ws, size_t ws_size,
                              hipStream_t stream) {
    const float* dij     = (const float*)d_in[0];
    const float* q       = (const float*)d_in[1];
    const float* g_ewald = (const float*)d_in[2];
    const int*   row     = (const int*)d_in[3];
    const int*   col     = (const int*)d_in[4];
    const int*   batch   = (const int*)d_in[5];

    int n_edges = in_sizes[0] / 3;
    int n_atoms = in_sizes[1];

    float* energy = (float*)d_out;               // [256]
    float* force  = (float*)d_out + N_GRAPHS_C;  // [n_atoms*3]

    int nb = (n_atoms + CHUNK - 1) >> CHUNK_LOG;            // 25
    int n4 = n_edges >> 2;
    int nblkA = (n4 + TILE_G - 1) / TILE_G;                 // 977

    size_t sz_partial = (size_t)nb * NSLICE * 2 * CHUNK * sizeof(unsigned); // 32.8 MB
    size_t sz_epart   = (size_t)nblkA * N_GRAPHS_C * sizeof(float);         // 1 MB
    size_t sz_cnt     = (size_t)nblkA * nb * sizeof(unsigned);
    size_t sz_ovf     = (size_t)3 * n_atoms * sizeof(float);
    size_t sz_qg      = (size_t)n_atoms * sizeof(float2);
    size_t fixed = ((sz_partial + 255) & ~(size_t)255) +
                   ((sz_epart   + 255) & ~(size_t)255) +
                   ((sz_cnt     + 255) & ~(size_t)255) +
                   ((sz_ovf     + 255) & ~(size_t)255) +
                   ((sz_qg      + 255) & ~(size_t)255) + 512;

    int cap = 0;
    if ((long long)ws_size > (long long)fixed) {
        long long c = ((long long)ws_size - (long long)fixed) /
                      ((long long)nblkA * nb * 8);
        c = (c / 32) * 32;
        // mean records/(block,bucket) ~655, sigma ~25 -> 768 is +4.5 sigma
        if (c > 1024) c = 1024;
        cap = (int)c;
    }

    bool fast = (nb <= MAXB) && ((n_edges & 3) == 0) && (cap >= 768);

    if (fast) {
        char* ws = (char*)d_ws;
        size_t off = 0;
        uint2*    records  = (uint2*)(ws + off);
        off += (size_t)nblkA * nb * cap * 8;   off = (off + 255) & ~(size_t)255;
        unsigned* partial  = (unsigned*)(ws + off);
        off += sz_partial;                     off = (off + 255) & ~(size_t)255;
        float*    e_part   = (float*)(ws + off);
        off += sz_epart;                       off = (off + 255) & ~(size_t)255;
        unsigned* cnt_tab  = (unsigned*)(ws + off);
        off += sz_cnt;                         off = (off + 255) & ~(size_t)255;
        float*    ovf      = (float*)(ws + off);
        off += sz_ovf;                         off = (off + 255) & ~(size_t)255;
        float2*   qg       = (float2*)(ws + off);

        hipMemsetAsync(ovf, 0, sz_ovf, stream);

        prep_qg<<<(n_atoms + 255) / 256, 256, 0, stream>>>(q, batch, qg, n_atoms);

        passA<<<nblkA, TPA, 0, stream>>>(
            dij, qg, g_ewald, row, col,
            records, cap, cnt_tab, e_part, ovf, n_edges, nb);

        passB<<<nb * NSLICE, TPBB, 0, stream>>>(
            records, cap, cnt_tab, partial, nblkA, nb, NSLICE);

        fin_force<<<(n_atoms + 255) / 256, 256, 0, stream>>>(
            partial, ovf, force, n_atoms, NSLICE);

        fin_energy<<<N_GRAPHS_C, 64, 0, stream>>>(e_part, energy, nblkA);
    } else {
        size_t need_chunk = (size_t)nb * NSLICE_FB * CHUNK * 4 * sizeof(float);
        if (ws_size >= need_chunk) {
            hipMemsetAsync(d_out, 0, N_GRAPHS_C * sizeof(float), stream);
            chunk_kernel<<<nb * NSLICE_FB, 1024, 0, stream>>>(
                dij, q, g_ewald, row, col, (float*)d_ws, n_edges, nb, NSLICE_FB);
            finalize_kernel<<<(n_atoms + 255) / 256, 256, 0, stream>>>(
                (const float*)d_ws, batch, energy, force, n_atoms, NSLICE_FB);
        }
    }
}